// Round 22
// baseline (188.665 us; speedup 1.0000x reference)
//
#include <hip/hip_runtime.h>
#include <hip/hip_bf16.h>
#include <stdint.h>

#define BB 2
#define SS 2048
#define DDIM 1024
#define HH 16
#define HDIM 64

typedef __hip_bfloat16 bf16;
typedef __bf16 bf16x8 __attribute__((ext_vector_type(8)));
typedef float f32x4 __attribute__((ext_vector_type(4)));
typedef short short8 __attribute__((ext_vector_type(8)));
typedef short s16x4 __attribute__((ext_vector_type(4)));

static __device__ __forceinline__ f32x4 mfma16(bf16x8 a, bf16x8 b, f32x4 c) {
  return __builtin_amdgcn_mfma_f32_16x16x32_bf16(a, b, c, 0, 0, 0);
}

static __device__ __forceinline__ void gload_lds16(const void* g, void* l) {
  __builtin_amdgcn_global_load_lds(
      (const __attribute__((address_space(1))) void*)g,
      (__attribute__((address_space(3))) void*)l, 16, 0, 0);
}

// ---------------- f32 -> bf16 flat convert (8 elems/thread) ----------------
__global__ __launch_bounds__(256) void cvt_k(const float* __restrict__ src,
                                             bf16* __restrict__ dst) {
  const int base = (blockIdx.x * 256 + threadIdx.x) * 8;
  float4 a = *reinterpret_cast<const float4*>(src + base);
  float4 b = *reinterpret_cast<const float4*>(src + base + 4);
  union {
    bf16 h[8];
    short8 v;
  } u;
  u.h[0] = __float2bfloat16(a.x);
  u.h[1] = __float2bfloat16(a.y);
  u.h[2] = __float2bfloat16(a.z);
  u.h[3] = __float2bfloat16(a.w);
  u.h[4] = __float2bfloat16(b.x);
  u.h[5] = __float2bfloat16(b.y);
  u.h[6] = __float2bfloat16(b.z);
  u.h[7] = __float2bfloat16(b.w);
  *reinterpret_cast<short8*>(dst + base) = u.v;
}

// -------- transpose+convert x4: dst[n][k] = (bf16)src[k][n], 1024x1024 -----
__global__ __launch_bounds__(256) void transpose_cvt4_k(
    const float* __restrict__ s0, const float* __restrict__ s1,
    const float* __restrict__ s2, const float* __restrict__ s3,
    bf16* __restrict__ d0, bf16* __restrict__ d1, bf16* __restrict__ d2,
    bf16* __restrict__ d3) {
  __shared__ float tile[64][65];
  const int zi = blockIdx.z;
  const float* src = zi == 0 ? s0 : (zi == 1 ? s1 : (zi == 2 ? s2 : s3));
  bf16* dst = zi == 0 ? d0 : (zi == 1 ? d1 : (zi == 2 ? d2 : d3));
  const int t = threadIdx.x;
  const int r = t >> 2, c0 = (t & 3) * 16;
  const int bx = blockIdx.x * 64, by = blockIdx.y * 64;
  const float* sp = src + (size_t)(by + r) * DDIM + bx + c0;
#pragma unroll
  for (int j = 0; j < 16; ++j) tile[r][c0 + j] = sp[j];
  __syncthreads();
  bf16* dp = dst + (size_t)(bx + r) * DDIM + by + c0;
#pragma unroll
  for (int j = 0; j < 16; ++j) dp[j] = __float2bfloat16(tile[c0 + j][r]);
}

// ---------------- pack key-padding mask into 64-bit words ----------------
__global__ __launch_bounds__(64) void mask_pack_k(
    const int* __restrict__ kpm, unsigned long long* __restrict__ mb) {
  const int i = blockIdx.x;  // 0..63 : b = i>>5, 64-key chunk = i&31
  const int b = i >> 5, c = i & 31;
  const unsigned long long bits =
      __ballot(kpm[b * SS + c * 64 + threadIdx.x] != 0);
  if (threadIdx.x == 0) mb[i] = bits;
}

// ---------------- GEMM: C[m][n] = A[m][:] . Bt[n][:]  (row-major, K=1024)
// MODE 0: N=3072, scatter bf16 to Q / K / Vt with per-section f32 bias
// MODE 1: N=1024, write f32 Of[m*1024+n] + bias b0
template <int MODE>
__global__ __launch_bounds__(256, 2) void gemm_bt(
    const bf16* __restrict__ A, const bf16* __restrict__ Bt,
    const float* __restrict__ b0, const float* __restrict__ b1,
    const float* __restrict__ b2, bf16* __restrict__ O0,
    bf16* __restrict__ O1, bf16* __restrict__ O2, float* __restrict__ Of) {
  constexpr int Kd = DDIM;
  __shared__ bf16x8 lA[128 * 8];
  __shared__ bf16x8 lB[128 * 8];
  const int tid = threadIdx.x;
  const int wave = tid >> 6, lane = tid & 63;
  const int l15 = lane & 15, l4 = lane >> 4;
  const int wm = wave >> 1, wn = wave & 1;
  const int m0 = blockIdx.x * 128, n0 = blockIdx.y * 128;
  const f32x4 z = {0.f, 0.f, 0.f, 0.f};
  f32x4 acc[4][4];
#pragma unroll
  for (int i = 0; i < 4; ++i)
#pragma unroll
    for (int j = 0; j < 4; ++j) acc[i][j] = z;

  for (int k0 = 0; k0 < Kd; k0 += 64) {
#pragma unroll
    for (int j = 0; j < 4; ++j) {
      const int slot = j * 256 + tid;
      const int r = slot >> 3, cs = slot & 7;
      const int c = cs ^ (r & 7);  // pre-swizzled global source, linear LDS dest
      gload_lds16(A + (size_t)(m0 + r) * Kd + k0 + c * 8,
                  &lA[j * 256 + wave * 64]);
      gload_lds16(Bt + (size_t)(n0 + r) * Kd + k0 + c * 8,
                  &lB[j * 256 + wave * 64]);
    }
    __syncthreads();
    bf16x8 af[2][4], bfr[2][4];
#pragma unroll
    for (int ks = 0; ks < 2; ++ks) {
#pragma unroll
      for (int i = 0; i < 4; ++i) {
        const int ra = wm * 64 + i * 16 + l15;
        af[ks][i] = lA[ra * 8 + ((ks * 4 + l4) ^ (ra & 7))];
        const int rb = wn * 64 + i * 16 + l15;
        bfr[ks][i] = lB[rb * 8 + ((ks * 4 + l4) ^ (rb & 7))];
      }
    }
#pragma unroll
    for (int ks = 0; ks < 2; ++ks)
#pragma unroll
      for (int i = 0; i < 4; ++i)
#pragma unroll
        for (int j = 0; j < 4; ++j)
          acc[i][j] = mfma16(af[ks][i], bfr[ks][j], acc[i][j]);
    __syncthreads();
  }

  // C row m = m0 + wm*64 + i*16 + l4*4 + r ; col n = n0 + wn*64 + j*16 + l15
#pragma unroll
  for (int i = 0; i < 4; ++i) {
    const int m = m0 + wm * 64 + i * 16 + l4 * 4;
#pragma unroll
    for (int j = 0; j < 4; ++j) {
      const int n = n0 + wn * 64 + j * 16 + l15;
      if (MODE == 1) {
        const float bb = b0[n];
#pragma unroll
        for (int r = 0; r < 4; ++r)
          Of[(size_t)(m + r) * DDIM + n] = acc[i][j][r] + bb;
      } else {
        const int sel = n >> 10, nn = n & 1023;
        const int h = nn >> 6, d = nn & 63;
        const float* bp = sel == 0 ? b0 : (sel == 1 ? b1 : b2);
        const float bb = bp[nn];
        const int b = m >> 11, s = m & 2047;
        if (sel == 2) {
          union {
            bf16 h4[4];
            s16x4 v;
          } u;
#pragma unroll
          for (int r = 0; r < 4; ++r)
            u.h4[r] = __float2bfloat16(acc[i][j][r] + bb);
          *reinterpret_cast<s16x4*>(
              &O2[((size_t)(b * HH + h) * HDIM + d) * SS + s]) = u.v;
        } else {
#pragma unroll
          for (int r = 0; r < 4; ++r) {
            const float val = acc[i][j][r] + bb;
            (sel ? O1 : O0)[((size_t)(b * HH + h) * SS + (s + r)) * HDIM + d] =
                __float2bfloat16(val);
          }
        }
      }
    }
  }
}

// ---------------- fused flash attention (GEMM-image LDS pipeline) ----------
// R19 per-64-key half-iteration, but TWO halves per barrier (128-key K/V
// tile, 16 steps instead of 32): halves the per-step lockstep barrier-drain
// cost; per-half code identical. Bias ping-pong stays 64-key-granular (same
// 8x f32x4 register footprint). K/V staged via gload_lds after halfB's reads
// of the same buffer. defer-max; setprio; XCD head-clustering. LDS 80KB ->
// 2 blocks/CU (16 waves/CU, same as R19's VGPR-limited occupancy).
__global__ __launch_bounds__(512, 1) void attn_k(
    const bf16* __restrict__ Qb, const bf16* __restrict__ Kb,
    const bf16* __restrict__ Vt, const float* __restrict__ bias,
    const unsigned long long* __restrict__ mbits, bf16* __restrict__ ctx) {
  __shared__ bf16x8 lK[2][1024];         // 2 x 128 keys x 64 hd (16KB each)
  __shared__ bf16x8 lV[2][1024];         // 2 x 64 d x 128 keys  (16KB each)
  __shared__ unsigned int plP[8 * 512];  // per-wave P scratch   (16KB)
  const int tid = threadIdx.x;
  const int wave = tid >> 6, lane = tid & 63;
  const int l15 = lane & 15, l4 = lane >> 4;
  // XCD-aware remap: hw block i -> logical bid (i%8)*64 + i/8 (bijective,
  // 512 = 8*64). XCD x owns 64 logical bids = 4 heads (K/V L2-resident).
  const int bid = ((blockIdx.x & 7) << 6) | (blockIdx.x >> 3);
  const int qblk = bid & 15, bh = bid >> 4;
  const int b = bh >> 4, h = bh & 15;
  const int q0b = qblk * 128;
  const int q0w = q0b + wave * 16;

  const bf16* Qp = Qb + ((size_t)bh * SS + q0w) * HDIM;
  const bf16* Kp = Kb + (size_t)bh * SS * HDIM;
  const bf16* Vp = Vt + (size_t)bh * HDIM * SS;
  const float* Bp = bias + (size_t)h * SS * SS + (size_t)(q0w + l15) * SS;
  unsigned int* plw = plP + wave * 512;

  // staging geometry (128-key tile = 1024 x 16B chunks, 2 per thread):
  // K slot s: r = s>>3 (key row 0..127), c = (s&7)^(r&7); calls s=tid,
  // s=tid+512 (row += 64, same XOR since 64&7==0).
  const int krs = tid >> 3, kcs = (tid & 7) ^ (krs & 7);
  // V slot s: d = s>>4 (0..63), c = (s&15)^(d&7); calls s=tid, s=tid+512.
  const int vd = tid >> 4, vcs = (tid & 15) ^ (vd & 7);

  // ---- prologue: stage tile 0 via gload_lds, bias(half A of step 0) ----
  gload_lds16(Kp + (size_t)krs * HDIM + kcs * 8, &lK[0][wave * 64]);
  gload_lds16(Kp + (size_t)(64 + krs) * HDIM + kcs * 8,
              &lK[0][512 + wave * 64]);
  gload_lds16(Vp + (size_t)vd * SS + vcs * 8, &lV[0][wave * 64]);
  gload_lds16(Vp + (size_t)(32 + vd) * SS + vcs * 8, &lV[0][512 + wave * 64]);

  f32x4 bA0 = *reinterpret_cast<const f32x4*>(Bp + 0 * 16 + l4 * 4);
  f32x4 bA1 = *reinterpret_cast<const f32x4*>(Bp + 1 * 16 + l4 * 4);
  f32x4 bA2 = *reinterpret_cast<const f32x4*>(Bp + 2 * 16 + l4 * 4);
  f32x4 bA3 = *reinterpret_cast<const f32x4*>(Bp + 3 * 16 + l4 * 4);
  f32x4 bB0 = bA0, bB1 = bA1, bB2 = bA2, bB3 = bA3;

  bf16x8 qf[2];
#pragma unroll
  for (int ks = 0; ks < 2; ++ks)
    qf[ks] = *reinterpret_cast<const bf16x8*>(Qp + (size_t)l15 * HDIM +
                                              ks * 32 + l4 * 8);
  const f32x4 z = {0.f, 0.f, 0.f, 0.f};
  f32x4 o[4];
#pragma unroll
  for (int dd = 0; dd < 4; ++dd) o[dd] = z;
  float mrow = -1e30f, lrow = 0.f;

  __syncthreads();  // tile 0 staged (barrier drains vmcnt)

#define JJROW(JJ, BC)                                                     \
  {                                                                       \
    const unsigned nib = (unsigned)(mb >> ((JJ)*16 + l4 * 4)) & 15u;      \
    _Pragma("unroll") for (int r = 0; r < 4; ++r) {                       \
      const float a = ((nib >> r) & 1u) ? -1e30f : (BC)[r];               \
      v[JJ][r] = fmaf(sc[JJ][r], 0.125f, a);                              \
      bm = fmaxf(bm, v[JJ][r]);                                           \
    }                                                                     \
  }

// One 64-key flash half-iteration. MW = mask word; KRO = K-row offset in
// tile (0/64); KH = V k-half (0/1); PF/KBN = bias prefetch into BN regs;
// SG/KBS = stage next 128-key tile (half B only, after all cur reads).
#define HALF(MW, KRO, KH, PF, KBN, BC0, BC1, BC2, BC3, BN0, BN1, BN2, BN3,     \
             SG, KBS)                                                          \
  {                                                                            \
    if (PF) {                                                                  \
      BN0 = *reinterpret_cast<const f32x4*>(Bp + (KBN) + 0 * 16 + l4 * 4);     \
      BN1 = *reinterpret_cast<const f32x4*>(Bp + (KBN) + 1 * 16 + l4 * 4);     \
      BN2 = *reinterpret_cast<const f32x4*>(Bp + (KBN) + 2 * 16 + l4 * 4);     \
      BN3 = *reinterpret_cast<const f32x4*>(Bp + (KBN) + 3 * 16 + l4 * 4);     \
    }                                                                          \
    f32x4 sc[4];                                                               \
    __builtin_amdgcn_s_setprio(1);                                             \
    _Pragma("unroll") for (int jj = 0; jj < 4; ++jj) {                         \
      const int R = (KRO) + jj * 16 + l15;                                     \
      bf16x8 kf0 = lK[cur][R * 8 + ((0 + l4) ^ (R & 7))];                      \
      bf16x8 kf1 = lK[cur][R * 8 + ((4 + l4) ^ (R & 7))];                      \
      f32x4 s = mfma16(kf0, qf[0], z);                                         \
      s = mfma16(kf1, qf[1], s);                                               \
      sc[jj] = s;                                                              \
    }                                                                          \
    __builtin_amdgcn_s_setprio(0);                                             \
    if (SG) { /* K-stage: after the last lK[cur] reads */                      \
      gload_lds16(Kp + (size_t)((KBS) + krs) * HDIM + kcs * 8,                 \
                  &lK[nxt][wave * 64]);                                        \
      gload_lds16(Kp + (size_t)((KBS) + 64 + krs) * HDIM + kcs * 8,            \
                  &lK[nxt][512 + wave * 64]);                                  \
    }                                                                          \
    const unsigned long long mb = mbits[(b << 5) + (MW)];                      \
    float v[4][4];                                                             \
    float bm = -1e30f;                                                         \
    JJROW(0, BC0)                                                              \
    JJROW(1, BC1)                                                              \
    JJROW(2, BC2)                                                              \
    JJROW(3, BC3)                                                              \
    bm = fmaxf(bm, __shfl_xor(bm, 16));                                        \
    bm = fmaxf(bm, __shfl_xor(bm, 32));                                        \
    const bool resc = __any(bm > mrow + 8.0f);                                 \
    float alpha = 1.0f;                                                        \
    if (resc) {                                                                \
      const float mn = fmaxf(mrow, bm);                                        \
      alpha = __expf(mrow - mn);                                               \
      mrow = mn;                                                               \
    }                                                                          \
    float ps = 0.f;                                                            \
    float p[4][4];                                                             \
    _Pragma("unroll") for (int jj = 0; jj < 4; ++jj)                           \
        _Pragma("unroll") for (int r = 0; r < 4; ++r) {                        \
      p[jj][r] = __expf(v[jj][r] - mrow);                                      \
      ps += p[jj][r];                                                          \
    }                                                                          \
    ps += __shfl_xor(ps, 16);                                                  \
    ps += __shfl_xor(ps, 32);                                                  \
    lrow = lrow * alpha + ps;                                                  \
    _Pragma("unroll") for (int jj = 0; jj < 4; ++jj) {                         \
      union {                                                                  \
        bf16 h4[4];                                                            \
        unsigned long long w;                                                  \
      } u;                                                                     \
      u.h4[0] = __float2bfloat16(p[jj][0]);                                    \
      u.h4[1] = __float2bfloat16(p[jj][1]);                                    \
      u.h4[2] = __float2bfloat16(p[jj][2]);                                    \
      u.h4[3] = __float2bfloat16(p[jj][3]);                                    \
      const int byte = (l15 * 128 + jj * 32 + l4 * 8) ^ ((l15 & 7) << 4);      \
      *reinterpret_cast<unsigned long long*>(                                  \
          reinterpret_cast<char*>(plw) + byte) = u.w;                          \
    }                                                                          \
    bf16x8 vfr[4][2];                                                          \
    _Pragma("unroll") for (int dd = 0; dd < 4; ++dd) {                         \
      const int D = dd * 16 + l15;                                             \
      vfr[dd][0] = lV[cur][D * 16 + (((KH)*8 + 0 + l4) ^ (D & 7))];            \
      vfr[dd][1] = lV[cur][D * 16 + (((KH)*8 + 4 + l4) ^ (D & 7))];            \
    }                                                                          \
    if (SG) { /* V-stage: after the last lV[cur] reads */                      \
      gload_lds16(Vp + (size_t)vd * SS + (KBS) + vcs * 8,                      \
                  &lV[nxt][wave * 64]);                                        \
      gload_lds16(Vp + (size_t)(32 + vd) * SS + (KBS) + vcs * 8,               \
                  &lV[nxt][512 + wave * 64]);                                  \
    }                                                                          \
    asm volatile("s_waitcnt lgkmcnt(0)" ::: "memory");                         \
    bf16x8 pfr[2];                                                             \
    _Pragma("unroll") for (int ks = 0; ks < 2; ++ks) {                         \
      const int byte = (l15 * 128 + ks * 64 + l4 * 16) ^ ((l15 & 7) << 4);     \
      pfr[ks] = *reinterpret_cast<const bf16x8*>(                              \
          reinterpret_cast<const char*>(plw) + byte);                          \
    }                                                                          \
    if (resc) {                                                                \
      float ar0 = __shfl(alpha, l4 * 4 + 0);                                   \
      float ar1 = __shfl(alpha, l4 * 4 + 1);                                   \
      float ar2 = __shfl(alpha, l4 * 4 + 2);                                   \
      float ar3 = __shfl(alpha, l4 * 4 + 3);                                   \
      _Pragma("unroll") for (int dd = 0; dd < 4; ++dd) {                       \
        o[dd][0] *= ar0;                                                       \
        o[dd][1] *= ar1;                                                       \
        o[dd][2] *= ar2;                                                       \
        o[dd][3] *= ar3;                                                       \
      }                                                                        \
    }                                                                          \
    __builtin_amdgcn_s_setprio(1);                                             \
    _Pragma("unroll") for (int dd = 0; dd < 4; ++dd) {                         \
      o[dd] = mfma16(pfr[0], vfr[dd][0], o[dd]);                               \
      o[dd] = mfma16(pfr[1], vfr[dd][1], o[dd]);                               \
    }                                                                          \
    __builtin_amdgcn_s_setprio(0);                                             \
  }

  for (int t = 0; t < 16; ++t) {
    const int cur = t & 1;
    const int nxt = cur ^ 1;
    const int kb = t * 128;
    const bool nl = t < 15;
    // half A: keys kb..kb+63; prefetch half-B bias; no staging
    HALF(2 * t, 0, 0, true, kb + 64, bA0, bA1, bA2, bA3, bB0, bB1, bB2, bB3,
         false, 0)
    // half B: keys kb+64..kb+127; prefetch next step's half-A bias; stage
    // next 128-key K/V tile after the final reads of the current buffers
    HALF(2 * t + 1, 64, 1, nl, (kb + 128) & (SS - 1), bB0, bB1, bB2, bB3, bA0,
         bA1, bA2, bA3, nl, kb + 128)
    __syncthreads();
  }
#undef HALF
#undef JJROW

  const float rl = 1.0f / lrow;
  float rlr[4];
#pragma unroll
  for (int r = 0; r < 4; ++r) rlr[r] = __shfl(rl, l4 * 4 + r);
#pragma unroll
  for (int dd = 0; dd < 4; ++dd) {
#pragma unroll
    for (int r = 0; r < 4; ++r) {
      const float val = o[dd][r] * rlr[r];
      const int s = q0w + l4 * 4 + r;
      ctx[((size_t)b * SS + s) * DDIM + h * HDIM + dd * 16 + l15] =
          __float2bfloat16(val);
    }
  }
}

extern "C" void kernel_launch(void* const* d_in, const int* in_sizes, int n_in,
                              void* d_out, int out_size, void* d_ws,
                              size_t ws_size, hipStream_t stream) {
  const float* x = (const float*)d_in[0];
  const float* abias = (const float*)d_in[1];
  const int* kpm = (const int*)d_in[2];
  const float* Wq = (const float*)d_in[3];
  const float* bq = (const float*)d_in[4];
  const float* Wk = (const float*)d_in[5];
  const float* bk = (const float*)d_in[6];
  const float* Wv = (const float*)d_in[7];
  const float* bv = (const float*)d_in[8];
  const float* Wo = (const float*)d_in[9];
  const float* bo = (const float*)d_in[10];
  float* out = (float*)d_out;

  char* ws = (char*)d_ws;
  bf16* xb = (bf16*)ws;                        // (B,S,D) bf16      8 MB
  bf16* Wt = (bf16*)(ws + 8388608);            // 3072x1024 bf16    6 MB
  bf16* Wot = (bf16*)(ws + 14680064);          // 1024x1024 bf16    2 MB
  bf16* Qb = (bf16*)(ws + 16777216);           // (B,H,S,HD)        8 MB
  bf16* Kb = (bf16*)(ws + 25165824);           // (B,H,S,HD)        8 MB
  bf16* Vtb = (bf16*)(ws + 33554432);          // (B,H,HD,S)        8 MB
  bf16* ctx = (bf16*)(ws + 41943040);          // (B,S,D) bf16      8 MB
  unsigned long long* mbits =
      (unsigned long long*)(ws + 50331648);    // 2*32 u64

  dim3 t256(256);
  cvt_k<<<dim3(2048), t256, 0, stream>>>(x, xb);
  transpose_cvt4_k<<<dim3(16, 16, 4), t256, 0, stream>>>(
      Wq, Wk, Wv, Wo, Wt, Wt + 1024 * 1024, Wt + 2 * 1024 * 1024, Wot);
  mask_pack_k<<<dim3(64), dim3(64), 0, stream>>>(kpm, mbits);

  gemm_bt<0><<<dim3(32, 24), t256, 0, stream>>>(xb, Wt, bq, bk, bv, Qb, Kb,
                                                Vtb, nullptr);
  attn_k<<<dim3(512), dim3(512), 0, stream>>>(Qb, Kb, Vtb, abias, mbits, ctx);
  gemm_bt<1><<<dim3(32, 8), t256, 0, stream>>>(ctx, Wot, bo, nullptr, nullptr,
                                               nullptr, nullptr, nullptr, out);
}

// Round 23
// 181.774 us; speedup vs baseline: 1.0379x; 1.0379x over previous
//
#include <hip/hip_runtime.h>
#include <hip/hip_bf16.h>
#include <stdint.h>

#define BB 2
#define SS 2048
#define DDIM 1024
#define HH 16
#define HDIM 64

typedef __hip_bfloat16 bf16;
typedef __bf16 bf16x8 __attribute__((ext_vector_type(8)));
typedef float f32x4 __attribute__((ext_vector_type(4)));
typedef short short8 __attribute__((ext_vector_type(8)));
typedef short s16x4 __attribute__((ext_vector_type(4)));

static __device__ __forceinline__ f32x4 mfma16(bf16x8 a, bf16x8 b, f32x4 c) {
  return __builtin_amdgcn_mfma_f32_16x16x32_bf16(a, b, c, 0, 0, 0);
}

static __device__ __forceinline__ void gload_lds16(const void* g, void* l) {
  __builtin_amdgcn_global_load_lds(
      (const __attribute__((address_space(1))) void*)g,
      (__attribute__((address_space(3))) void*)l, 16, 0, 0);
}

// ---------------- f32 -> bf16 flat convert (8 elems/thread) ----------------
__global__ __launch_bounds__(256) void cvt_k(const float* __restrict__ src,
                                             bf16* __restrict__ dst) {
  const int base = (blockIdx.x * 256 + threadIdx.x) * 8;
  float4 a = *reinterpret_cast<const float4*>(src + base);
  float4 b = *reinterpret_cast<const float4*>(src + base + 4);
  union {
    bf16 h[8];
    short8 v;
  } u;
  u.h[0] = __float2bfloat16(a.x);
  u.h[1] = __float2bfloat16(a.y);
  u.h[2] = __float2bfloat16(a.z);
  u.h[3] = __float2bfloat16(a.w);
  u.h[4] = __float2bfloat16(b.x);
  u.h[5] = __float2bfloat16(b.y);
  u.h[6] = __float2bfloat16(b.z);
  u.h[7] = __float2bfloat16(b.w);
  *reinterpret_cast<short8*>(dst + base) = u.v;
}

// -------- transpose+convert x4: dst[n][k] = (bf16)src[k][n], 1024x1024 -----
__global__ __launch_bounds__(256) void transpose_cvt4_k(
    const float* __restrict__ s0, const float* __restrict__ s1,
    const float* __restrict__ s2, const float* __restrict__ s3,
    bf16* __restrict__ d0, bf16* __restrict__ d1, bf16* __restrict__ d2,
    bf16* __restrict__ d3) {
  __shared__ float tile[64][65];
  const int zi = blockIdx.z;
  const float* src = zi == 0 ? s0 : (zi == 1 ? s1 : (zi == 2 ? s2 : s3));
  bf16* dst = zi == 0 ? d0 : (zi == 1 ? d1 : (zi == 2 ? d2 : d3));
  const int t = threadIdx.x;
  const int r = t >> 2, c0 = (t & 3) * 16;
  const int bx = blockIdx.x * 64, by = blockIdx.y * 64;
  const float* sp = src + (size_t)(by + r) * DDIM + bx + c0;
#pragma unroll
  for (int j = 0; j < 16; ++j) tile[r][c0 + j] = sp[j];
  __syncthreads();
  bf16* dp = dst + (size_t)(bx + r) * DDIM + by + c0;
#pragma unroll
  for (int j = 0; j < 16; ++j) dp[j] = __float2bfloat16(tile[c0 + j][r]);
}

// ---------------- pack key-padding mask into 64-bit words ----------------
__global__ __launch_bounds__(64) void mask_pack_k(
    const int* __restrict__ kpm, unsigned long long* __restrict__ mb) {
  const int i = blockIdx.x;  // 0..63 : b = i>>5, 64-key chunk = i&31
  const int b = i >> 5, c = i & 31;
  const unsigned long long bits =
      __ballot(kpm[b * SS + c * 64 + threadIdx.x] != 0);
  if (threadIdx.x == 0) mb[i] = bits;
}

// ---------------- GEMM: C[m][n] = A[m][:] . Bt[n][:]  (row-major, K=1024)
// MODE 0: N=3072, scatter bf16 to Q / K / Vt with per-section f32 bias
// MODE 1: N=1024, write f32 Of[m*1024+n] + bias b0
template <int MODE>
__global__ __launch_bounds__(256, 2) void gemm_bt(
    const bf16* __restrict__ A, const bf16* __restrict__ Bt,
    const float* __restrict__ b0, const float* __restrict__ b1,
    const float* __restrict__ b2, bf16* __restrict__ O0,
    bf16* __restrict__ O1, bf16* __restrict__ O2, float* __restrict__ Of) {
  constexpr int Kd = DDIM;
  __shared__ bf16x8 lA[128 * 8];
  __shared__ bf16x8 lB[128 * 8];
  const int tid = threadIdx.x;
  const int wave = tid >> 6, lane = tid & 63;
  const int l15 = lane & 15, l4 = lane >> 4;
  const int wm = wave >> 1, wn = wave & 1;
  const int m0 = blockIdx.x * 128, n0 = blockIdx.y * 128;
  const f32x4 z = {0.f, 0.f, 0.f, 0.f};
  f32x4 acc[4][4];
#pragma unroll
  for (int i = 0; i < 4; ++i)
#pragma unroll
    for (int j = 0; j < 4; ++j) acc[i][j] = z;

  for (int k0 = 0; k0 < Kd; k0 += 64) {
#pragma unroll
    for (int j = 0; j < 4; ++j) {
      const int slot = j * 256 + tid;
      const int r = slot >> 3, cs = slot & 7;
      const int c = cs ^ (r & 7);  // pre-swizzled global source, linear LDS dest
      gload_lds16(A + (size_t)(m0 + r) * Kd + k0 + c * 8,
                  &lA[j * 256 + wave * 64]);
      gload_lds16(Bt + (size_t)(n0 + r) * Kd + k0 + c * 8,
                  &lB[j * 256 + wave * 64]);
    }
    __syncthreads();
    bf16x8 af[2][4], bfr[2][4];
#pragma unroll
    for (int ks = 0; ks < 2; ++ks) {
#pragma unroll
      for (int i = 0; i < 4; ++i) {
        const int ra = wm * 64 + i * 16 + l15;
        af[ks][i] = lA[ra * 8 + ((ks * 4 + l4) ^ (ra & 7))];
        const int rb = wn * 64 + i * 16 + l15;
        bfr[ks][i] = lB[rb * 8 + ((ks * 4 + l4) ^ (rb & 7))];
      }
    }
#pragma unroll
    for (int ks = 0; ks < 2; ++ks)
#pragma unroll
      for (int i = 0; i < 4; ++i)
#pragma unroll
        for (int j = 0; j < 4; ++j)
          acc[i][j] = mfma16(af[ks][i], bfr[ks][j], acc[i][j]);
    __syncthreads();
  }

  // C row m = m0 + wm*64 + i*16 + l4*4 + r ; col n = n0 + wn*64 + j*16 + l15
#pragma unroll
  for (int i = 0; i < 4; ++i) {
    const int m = m0 + wm * 64 + i * 16 + l4 * 4;
#pragma unroll
    for (int j = 0; j < 4; ++j) {
      const int n = n0 + wn * 64 + j * 16 + l15;
      if (MODE == 1) {
        const float bb = b0[n];
#pragma unroll
        for (int r = 0; r < 4; ++r)
          Of[(size_t)(m + r) * DDIM + n] = acc[i][j][r] + bb;
      } else {
        const int sel = n >> 10, nn = n & 1023;
        const int h = nn >> 6, d = nn & 63;
        const float* bp = sel == 0 ? b0 : (sel == 1 ? b1 : b2);
        const float bb = bp[nn];
        const int b = m >> 11, s = m & 2047;
        if (sel == 2) {
          union {
            bf16 h4[4];
            s16x4 v;
          } u;
#pragma unroll
          for (int r = 0; r < 4; ++r)
            u.h4[r] = __float2bfloat16(acc[i][j][r] + bb);
          *reinterpret_cast<s16x4*>(
              &O2[((size_t)(b * HH + h) * HDIM + d) * SS + s]) = u.v;
        } else {
#pragma unroll
          for (int r = 0; r < 4; ++r) {
            const float val = acc[i][j][r] + bb;
            (sel ? O1 : O0)[((size_t)(b * HH + h) * SS + (s + r)) * HDIM + d] =
                __float2bfloat16(val);
          }
        }
      }
    }
  }
}

// ---------------- fused flash attention (GEMM-image LDS pipeline) ----------
// Best-verified configuration (R19/R21, 182us total): 512-thread blocks
// (8 waves, 128 q-rows per block, grid 512) — the staged K/V tile serves 8
// waves; gload_lds double-buffered staging issued AFTER this step's reads of
// the same buffer; bias in NAMED f32x4 ping-pong regs; defer-max (THR=8);
// setprio around MFMA clusters; XCD head-clustering swizzle (K/V
// L2-resident); P-writes merged to ds_write_b64. LDS 48KB. One
// __syncthreads per step.
__global__ __launch_bounds__(512, 1) void attn_k(
    const bf16* __restrict__ Qb, const bf16* __restrict__ Kb,
    const bf16* __restrict__ Vt, const float* __restrict__ bias,
    const unsigned long long* __restrict__ mbits, bf16* __restrict__ ctx) {
  __shared__ bf16x8 lK[2][512];          // 2 x 64 keys x 64 hd  (8KB each)
  __shared__ bf16x8 lV[2][512];          // 2 x 64 d x 64 keys   (8KB each)
  __shared__ unsigned int plP[8 * 512];  // per-wave P scratch   (16KB)
  const int tid = threadIdx.x;
  const int wave = tid >> 6, lane = tid & 63;
  const int l15 = lane & 15, l4 = lane >> 4;
  // XCD-aware remap: hw block i -> logical bid (i%8)*64 + i/8 (bijective,
  // 512 = 8*64). XCD x owns 64 logical bids = 4 heads (K/V L2-resident).
  const int bid = ((blockIdx.x & 7) << 6) | (blockIdx.x >> 3);
  const int qblk = bid & 15, bh = bid >> 4;
  const int b = bh >> 4, h = bh & 15;
  const int q0b = qblk * 128;
  const int q0w = q0b + wave * 16;

  const bf16* Qp = Qb + ((size_t)bh * SS + q0w) * HDIM;
  const bf16* Kp = Kb + (size_t)bh * SS * HDIM;
  const bf16* Vp = Vt + (size_t)bh * HDIM * SS;
  const float* Bp = bias + (size_t)h * SS * SS + (size_t)(q0w + l15) * SS;
  unsigned int* plw = plP + wave * 512;

  // staging: one 16B K chunk + one V chunk per thread; LDS slot s = tid,
  // global chunk (r = s>>3, c = (s&7) ^ (r&7)); dest = wave-uniform base.
  const int rs0 = tid >> 3, cs0 = (tid & 7) ^ (rs0 & 7);

  // ---- prologue: stage tile 0 via gload_lds, bias -> regs ----
  gload_lds16(Kp + (size_t)rs0 * HDIM + cs0 * 8, &lK[0][wave * 64]);
  gload_lds16(Vp + (size_t)rs0 * SS + cs0 * 8, &lV[0][wave * 64]);

  f32x4 bA0 = *reinterpret_cast<const f32x4*>(Bp + 0 * 16 + l4 * 4);
  f32x4 bA1 = *reinterpret_cast<const f32x4*>(Bp + 1 * 16 + l4 * 4);
  f32x4 bA2 = *reinterpret_cast<const f32x4*>(Bp + 2 * 16 + l4 * 4);
  f32x4 bA3 = *reinterpret_cast<const f32x4*>(Bp + 3 * 16 + l4 * 4);
  f32x4 bB0 = bA0, bB1 = bA1, bB2 = bA2, bB3 = bA3;

  bf16x8 qf[2];
#pragma unroll
  for (int ks = 0; ks < 2; ++ks)
    qf[ks] = *reinterpret_cast<const bf16x8*>(Qp + (size_t)l15 * HDIM +
                                              ks * 32 + l4 * 8);
  const f32x4 z = {0.f, 0.f, 0.f, 0.f};
  f32x4 o[4];
#pragma unroll
  for (int dd = 0; dd < 4; ++dd) o[dd] = z;
  float mrow = -1e30f, lrow = 0.f;

  __syncthreads();  // tile 0 staged (barrier drains vmcnt)

#define JJROW(JJ, BC)                                                     \
  {                                                                       \
    const unsigned nib = (unsigned)(mb >> ((JJ)*16 + l4 * 4)) & 15u;      \
    _Pragma("unroll") for (int r = 0; r < 4; ++r) {                       \
      const float a = ((nib >> r) & 1u) ? -1e30f : (BC)[r];               \
      v[JJ][r] = fmaf(sc[JJ][r], 0.125f, a);                              \
      bm = fmaxf(bm, v[JJ][r]);                                           \
    }                                                                     \
  }

#define STEP(T, BC0, BC1, BC2, BC3, BN0, BN1, BN2, BN3)                        \
  {                                                                            \
    const int cur = (T)&1;                                                     \
    const int nxt = cur ^ 1;                                                   \
    const int kbn = ((T) + 1) * 64;                                            \
    const bool pf = (T) < 31;                                                  \
    if (pf) {                                                                  \
      BN0 = *reinterpret_cast<const f32x4*>(Bp + kbn + 0 * 16 + l4 * 4);       \
      BN1 = *reinterpret_cast<const f32x4*>(Bp + kbn + 1 * 16 + l4 * 4);       \
      BN2 = *reinterpret_cast<const f32x4*>(Bp + kbn + 2 * 16 + l4 * 4);       \
      BN3 = *reinterpret_cast<const f32x4*>(Bp + kbn + 3 * 16 + l4 * 4);       \
    }                                                                          \
    f32x4 sc[4];                                                               \
    __builtin_amdgcn_s_setprio(1);                                             \
    _Pragma("unroll") for (int jj = 0; jj < 4; ++jj) {                         \
      const int R = jj * 16 + l15;                                             \
      bf16x8 kf0 = lK[cur][R * 8 + ((0 + l4) ^ (R & 7))];                      \
      bf16x8 kf1 = lK[cur][R * 8 + ((4 + l4) ^ (R & 7))];                      \
      f32x4 s = mfma16(kf0, qf[0], z);                                         \
      s = mfma16(kf1, qf[1], s);                                               \
      sc[jj] = s;                                                              \
    }                                                                          \
    __builtin_amdgcn_s_setprio(0);                                             \
    if (pf) { /* K-stage: after all lK[cur] reads */                           \
      gload_lds16(Kp + (size_t)(kbn + rs0) * HDIM + cs0 * 8,                   \
                  &lK[nxt][wave * 64]);                                        \
    }                                                                          \
    const unsigned long long mb = mbits[(b << 5) + (T)];                       \
    float v[4][4];                                                             \
    float bm = -1e30f;                                                         \
    JJROW(0, BC0)                                                              \
    JJROW(1, BC1)                                                              \
    JJROW(2, BC2)                                                              \
    JJROW(3, BC3)                                                              \
    bm = fmaxf(bm, __shfl_xor(bm, 16));                                        \
    bm = fmaxf(bm, __shfl_xor(bm, 32));                                        \
    const bool resc = __any(bm > mrow + 8.0f);                                 \
    float alpha = 1.0f;                                                        \
    if (resc) {                                                                \
      const float mn = fmaxf(mrow, bm);                                        \
      alpha = __expf(mrow - mn);                                               \
      mrow = mn;                                                               \
    }                                                                          \
    float ps = 0.f;                                                            \
    float p[4][4];                                                             \
    _Pragma("unroll") for (int jj = 0; jj < 4; ++jj)                           \
        _Pragma("unroll") for (int r = 0; r < 4; ++r) {                        \
      p[jj][r] = __expf(v[jj][r] - mrow);                                      \
      ps += p[jj][r];                                                          \
    }                                                                          \
    ps += __shfl_xor(ps, 16);                                                  \
    ps += __shfl_xor(ps, 32);                                                  \
    lrow = lrow * alpha + ps;                                                  \
    _Pragma("unroll") for (int jj = 0; jj < 4; ++jj) {                         \
      union {                                                                  \
        bf16 h4[4];                                                            \
        unsigned long long w;                                                  \
      } u;                                                                     \
      u.h4[0] = __float2bfloat16(p[jj][0]);                                    \
      u.h4[1] = __float2bfloat16(p[jj][1]);                                    \
      u.h4[2] = __float2bfloat16(p[jj][2]);                                    \
      u.h4[3] = __float2bfloat16(p[jj][3]);                                    \
      const int byte = (l15 * 128 + jj * 32 + l4 * 8) ^ ((l15 & 7) << 4);      \
      *reinterpret_cast<unsigned long long*>(                                  \
          reinterpret_cast<char*>(plw) + byte) = u.w;                          \
    }                                                                          \
    bf16x8 vfr[4][2];                                                          \
    _Pragma("unroll") for (int dd = 0; dd < 4; ++dd) {                         \
      const int D = dd * 16 + l15;                                             \
      vfr[dd][0] = lV[cur][D * 8 + ((0 + l4) ^ (D & 7))];                      \
      vfr[dd][1] = lV[cur][D * 8 + ((4 + l4) ^ (D & 7))];                      \
    }                                                                          \
    if (pf) { /* V-stage: after all lV[cur] reads */                           \
      gload_lds16(Vp + (size_t)rs0 * SS + kbn + cs0 * 8,                       \
                  &lV[nxt][wave * 64]);                                        \
    }                                                                          \
    asm volatile("s_waitcnt lgkmcnt(0)" ::: "memory");                         \
    bf16x8 pfr[2];                                                             \
    _Pragma("unroll") for (int ks = 0; ks < 2; ++ks) {                         \
      const int byte = (l15 * 128 + ks * 64 + l4 * 16) ^ ((l15 & 7) << 4);     \
      pfr[ks] = *reinterpret_cast<const bf16x8*>(                              \
          reinterpret_cast<const char*>(plw) + byte);                          \
    }                                                                          \
    if (resc) {                                                                \
      float ar0 = __shfl(alpha, l4 * 4 + 0);                                   \
      float ar1 = __shfl(alpha, l4 * 4 + 1);                                   \
      float ar2 = __shfl(alpha, l4 * 4 + 2);                                   \
      float ar3 = __shfl(alpha, l4 * 4 + 3);                                   \
      _Pragma("unroll") for (int dd = 0; dd < 4; ++dd) {                       \
        o[dd][0] *= ar0;                                                       \
        o[dd][1] *= ar1;                                                       \
        o[dd][2] *= ar2;                                                       \
        o[dd][3] *= ar3;                                                       \
      }                                                                        \
    }                                                                          \
    __builtin_amdgcn_s_setprio(1);                                             \
    _Pragma("unroll") for (int dd = 0; dd < 4; ++dd) {                         \
      o[dd] = mfma16(pfr[0], vfr[dd][0], o[dd]);                               \
      o[dd] = mfma16(pfr[1], vfr[dd][1], o[dd]);                               \
    }                                                                          \
    __builtin_amdgcn_s_setprio(0);                                             \
    __syncthreads();                                                           \
  }

  for (int t2 = 0; t2 < 16; ++t2) {
    const int te = t2 * 2;
    STEP(te, bA0, bA1, bA2, bA3, bB0, bB1, bB2, bB3)
    STEP(te + 1, bB0, bB1, bB2, bB3, bA0, bA1, bA2, bA3)
  }
#undef STEP
#undef JJROW

  const float rl = 1.0f / lrow;
  float rlr[4];
#pragma unroll
  for (int r = 0; r < 4; ++r) rlr[r] = __shfl(rl, l4 * 4 + r);
#pragma unroll
  for (int dd = 0; dd < 4; ++dd) {
#pragma unroll
    for (int r = 0; r < 4; ++r) {
      const float val = o[dd][r] * rlr[r];
      const int s = q0w + l4 * 4 + r;
      ctx[((size_t)b * SS + s) * DDIM + h * HDIM + dd * 16 + l15] =
          __float2bfloat16(val);
    }
  }
}

extern "C" void kernel_launch(void* const* d_in, const int* in_sizes, int n_in,
                              void* d_out, int out_size, void* d_ws,
                              size_t ws_size, hipStream_t stream) {
  const float* x = (const float*)d_in[0];
  const float* abias = (const float*)d_in[1];
  const int* kpm = (const int*)d_in[2];
  const float* Wq = (const float*)d_in[3];
  const float* bq = (const float*)d_in[4];
  const float* Wk = (const float*)d_in[5];
  const float* bk = (const float*)d_in[6];
  const float* Wv = (const float*)d_in[7];
  const float* bv = (const float*)d_in[8];
  const float* Wo = (const float*)d_in[9];
  const float* bo = (const float*)d_in[10];
  float* out = (float*)d_out;

  char* ws = (char*)d_ws;
  bf16* xb = (bf16*)ws;                        // (B,S,D) bf16      8 MB
  bf16* Wt = (bf16*)(ws + 8388608);            // 3072x1024 bf16    6 MB
  bf16* Wot = (bf16*)(ws + 14680064);          // 1024x1024 bf16    2 MB
  bf16* Qb = (bf16*)(ws + 16777216);           // (B,H,S,HD)        8 MB
  bf16* Kb = (bf16*)(ws + 25165824);           // (B,H,S,HD)        8 MB
  bf16* Vtb = (bf16*)(ws + 33554432);          // (B,H,HD,S)        8 MB
  bf16* ctx = (bf16*)(ws + 41943040);          // (B,S,D) bf16      8 MB
  unsigned long long* mbits =
      (unsigned long long*)(ws + 50331648);    // 2*32 u64

  dim3 t256(256);
  cvt_k<<<dim3(2048), t256, 0, stream>>>(x, xb);
  transpose_cvt4_k<<<dim3(16, 16, 4), t256, 0, stream>>>(
      Wq, Wk, Wv, Wo, Wt, Wt + 1024 * 1024, Wt + 2 * 1024 * 1024, Wot);
  mask_pack_k<<<dim3(64), dim3(64), 0, stream>>>(kpm, mbits);

  gemm_bt<0><<<dim3(32, 24), t256, 0, stream>>>(xb, Wt, bq, bk, bv, Qb, Kb,
                                                Vtb, nullptr);
  attn_k<<<dim3(512), dim3(512), 0, stream>>>(Qb, Kb, Vtb, abias, mbits, ctx);
  gemm_bt<1><<<dim3(32, 8), t256, 0, stream>>>(ctx, Wot, bo, nullptr, nullptr,
                                               nullptr, nullptr, nullptr, out);
}

// Round 24
// 181.497 us; speedup vs baseline: 1.0395x; 1.0015x over previous
//
#include <hip/hip_runtime.h>
#include <hip/hip_bf16.h>
#include <stdint.h>

#define BB 2
#define SS 2048
#define DDIM 1024
#define HH 16
#define HDIM 64

typedef __hip_bfloat16 bf16;
typedef __bf16 bf16x8 __attribute__((ext_vector_type(8)));
typedef float f32x4 __attribute__((ext_vector_type(4)));
typedef short short8 __attribute__((ext_vector_type(8)));
typedef short s16x4 __attribute__((ext_vector_type(4)));

static __device__ __forceinline__ f32x4 mfma16(bf16x8 a, bf16x8 b, f32x4 c) {
  return __builtin_amdgcn_mfma_f32_16x16x32_bf16(a, b, c, 0, 0, 0);
}

static __device__ __forceinline__ void gload_lds16(const void* g, void* l) {
  __builtin_amdgcn_global_load_lds(
      (const __attribute__((address_space(1))) void*)g,
      (__attribute__((address_space(3))) void*)l, 16, 0, 0);
}

// ---------------- f32 -> bf16 flat convert (8 elems/thread) ----------------
__global__ __launch_bounds__(256) void cvt_k(const float* __restrict__ src,
                                             bf16* __restrict__ dst) {
  const int base = (blockIdx.x * 256 + threadIdx.x) * 8;
  float4 a = *reinterpret_cast<const float4*>(src + base);
  float4 b = *reinterpret_cast<const float4*>(src + base + 4);
  union {
    bf16 h[8];
    short8 v;
  } u;
  u.h[0] = __float2bfloat16(a.x);
  u.h[1] = __float2bfloat16(a.y);
  u.h[2] = __float2bfloat16(a.z);
  u.h[3] = __float2bfloat16(a.w);
  u.h[4] = __float2bfloat16(b.x);
  u.h[5] = __float2bfloat16(b.y);
  u.h[6] = __float2bfloat16(b.z);
  u.h[7] = __float2bfloat16(b.w);
  *reinterpret_cast<short8*>(dst + base) = u.v;
}

// -------- transpose+convert x4: dst[n][k] = (bf16)src[k][n], 1024x1024 -----
__global__ __launch_bounds__(256) void transpose_cvt4_k(
    const float* __restrict__ s0, const float* __restrict__ s1,
    const float* __restrict__ s2, const float* __restrict__ s3,
    bf16* __restrict__ d0, bf16* __restrict__ d1, bf16* __restrict__ d2,
    bf16* __restrict__ d3) {
  __shared__ float tile[64][65];
  const int zi = blockIdx.z;
  const float* src = zi == 0 ? s0 : (zi == 1 ? s1 : (zi == 2 ? s2 : s3));
  bf16* dst = zi == 0 ? d0 : (zi == 1 ? d1 : (zi == 2 ? d2 : d3));
  const int t = threadIdx.x;
  const int r = t >> 2, c0 = (t & 3) * 16;
  const int bx = blockIdx.x * 64, by = blockIdx.y * 64;
  const float* sp = src + (size_t)(by + r) * DDIM + bx + c0;
#pragma unroll
  for (int j = 0; j < 16; ++j) tile[r][c0 + j] = sp[j];
  __syncthreads();
  bf16* dp = dst + (size_t)(bx + r) * DDIM + by + c0;
#pragma unroll
  for (int j = 0; j < 16; ++j) dp[j] = __float2bfloat16(tile[c0 + j][r]);
}

// ---------------- pack key-padding mask into 64-bit words ----------------
__global__ __launch_bounds__(64) void mask_pack_k(
    const int* __restrict__ kpm, unsigned long long* __restrict__ mb) {
  const int i = blockIdx.x;  // 0..63 : b = i>>5, 64-key chunk = i&31
  const int b = i >> 5, c = i & 31;
  const unsigned long long bits =
      __ballot(kpm[b * SS + c * 64 + threadIdx.x] != 0);
  if (threadIdx.x == 0) mb[i] = bits;
}

// ---------------- GEMM: C[m][n] = A[m][:] . Bt[n][:]  (row-major, K=1024)
// MODE 0: N=3072, scatter bf16 to Q / K / Vt with per-section f32 bias
// MODE 1: N=1024, write f32 Of[m*1024+n] + bias b0
template <int MODE>
__global__ __launch_bounds__(256, 2) void gemm_bt(
    const bf16* __restrict__ A, const bf16* __restrict__ Bt,
    const float* __restrict__ b0, const float* __restrict__ b1,
    const float* __restrict__ b2, bf16* __restrict__ O0,
    bf16* __restrict__ O1, bf16* __restrict__ O2, float* __restrict__ Of) {
  constexpr int Kd = DDIM;
  __shared__ bf16x8 lA[128 * 8];
  __shared__ bf16x8 lB[128 * 8];
  const int tid = threadIdx.x;
  const int wave = tid >> 6, lane = tid & 63;
  const int l15 = lane & 15, l4 = lane >> 4;
  const int wm = wave >> 1, wn = wave & 1;
  const int m0 = blockIdx.x * 128, n0 = blockIdx.y * 128;
  const f32x4 z = {0.f, 0.f, 0.f, 0.f};
  f32x4 acc[4][4];
#pragma unroll
  for (int i = 0; i < 4; ++i)
#pragma unroll
    for (int j = 0; j < 4; ++j) acc[i][j] = z;

  for (int k0 = 0; k0 < Kd; k0 += 64) {
#pragma unroll
    for (int j = 0; j < 4; ++j) {
      const int slot = j * 256 + tid;
      const int r = slot >> 3, cs = slot & 7;
      const int c = cs ^ (r & 7);  // pre-swizzled global source, linear LDS dest
      gload_lds16(A + (size_t)(m0 + r) * Kd + k0 + c * 8,
                  &lA[j * 256 + wave * 64]);
      gload_lds16(Bt + (size_t)(n0 + r) * Kd + k0 + c * 8,
                  &lB[j * 256 + wave * 64]);
    }
    __syncthreads();
    bf16x8 af[2][4], bfr[2][4];
#pragma unroll
    for (int ks = 0; ks < 2; ++ks) {
#pragma unroll
      for (int i = 0; i < 4; ++i) {
        const int ra = wm * 64 + i * 16 + l15;
        af[ks][i] = lA[ra * 8 + ((ks * 4 + l4) ^ (ra & 7))];
        const int rb = wn * 64 + i * 16 + l15;
        bfr[ks][i] = lB[rb * 8 + ((ks * 4 + l4) ^ (rb & 7))];
      }
    }
#pragma unroll
    for (int ks = 0; ks < 2; ++ks)
#pragma unroll
      for (int i = 0; i < 4; ++i)
#pragma unroll
        for (int j = 0; j < 4; ++j)
          acc[i][j] = mfma16(af[ks][i], bfr[ks][j], acc[i][j]);
    __syncthreads();
  }

  // C row m = m0 + wm*64 + i*16 + l4*4 + r ; col n = n0 + wn*64 + j*16 + l15
#pragma unroll
  for (int i = 0; i < 4; ++i) {
    const int m = m0 + wm * 64 + i * 16 + l4 * 4;
#pragma unroll
    for (int j = 0; j < 4; ++j) {
      const int n = n0 + wn * 64 + j * 16 + l15;
      if (MODE == 1) {
        const float bb = b0[n];
#pragma unroll
        for (int r = 0; r < 4; ++r)
          Of[(size_t)(m + r) * DDIM + n] = acc[i][j][r] + bb;
      } else {
        const int sel = n >> 10, nn = n & 1023;
        const int h = nn >> 6, d = nn & 63;
        const float* bp = sel == 0 ? b0 : (sel == 1 ? b1 : b2);
        const float bb = bp[nn];
        const int b = m >> 11, s = m & 2047;
        if (sel == 2) {
          union {
            bf16 h4[4];
            s16x4 v;
          } u;
#pragma unroll
          for (int r = 0; r < 4; ++r)
            u.h4[r] = __float2bfloat16(acc[i][j][r] + bb);
          *reinterpret_cast<s16x4*>(
              &O2[((size_t)(b * HH + h) * HDIM + d) * SS + s]) = u.v;
        } else {
#pragma unroll
          for (int r = 0; r < 4; ++r) {
            const float val = acc[i][j][r] + bb;
            (sel ? O1 : O0)[((size_t)(b * HH + h) * SS + (s + r)) * HDIM + d] =
                __float2bfloat16(val);
          }
        }
      }
    }
  }
}

// ---------------- fused flash attention (GEMM-image LDS pipeline) ----------
// Final verified configuration (182us total, reproduced 3x): 512-thread
// blocks (8 waves, 128 q-rows per block, grid 512) — the staged K/V tile
// serves 8 waves; gload_lds double-buffered staging issued AFTER this step's
// reads of the same buffer; bias in NAMED f32x4 ping-pong regs; defer-max
// (THR=8); setprio around MFMA clusters; XCD head-clustering swizzle (K/V
// L2-resident); P-writes merged to ds_write_b64. LDS 48KB. One
// __syncthreads per step.
__global__ __launch_bounds__(512, 1) void attn_k(
    const bf16* __restrict__ Qb, const bf16* __restrict__ Kb,
    const bf16* __restrict__ Vt, const float* __restrict__ bias,
    const unsigned long long* __restrict__ mbits, bf16* __restrict__ ctx) {
  __shared__ bf16x8 lK[2][512];          // 2 x 64 keys x 64 hd  (8KB each)
  __shared__ bf16x8 lV[2][512];          // 2 x 64 d x 64 keys   (8KB each)
  __shared__ unsigned int plP[8 * 512];  // per-wave P scratch   (16KB)
  const int tid = threadIdx.x;
  const int wave = tid >> 6, lane = tid & 63;
  const int l15 = lane & 15, l4 = lane >> 4;
  // XCD-aware remap: hw block i -> logical bid (i%8)*64 + i/8 (bijective,
  // 512 = 8*64). XCD x owns 64 logical bids = 4 heads (K/V L2-resident).
  const int bid = ((blockIdx.x & 7) << 6) | (blockIdx.x >> 3);
  const int qblk = bid & 15, bh = bid >> 4;
  const int b = bh >> 4, h = bh & 15;
  const int q0b = qblk * 128;
  const int q0w = q0b + wave * 16;

  const bf16* Qp = Qb + ((size_t)bh * SS + q0w) * HDIM;
  const bf16* Kp = Kb + (size_t)bh * SS * HDIM;
  const bf16* Vp = Vt + (size_t)bh * HDIM * SS;
  const float* Bp = bias + (size_t)h * SS * SS + (size_t)(q0w + l15) * SS;
  unsigned int* plw = plP + wave * 512;

  // staging: one 16B K chunk + one V chunk per thread; LDS slot s = tid,
  // global chunk (r = s>>3, c = (s&7) ^ (r&7)); dest = wave-uniform base.
  const int rs0 = tid >> 3, cs0 = (tid & 7) ^ (rs0 & 7);

  // ---- prologue: stage tile 0 via gload_lds, bias -> regs ----
  gload_lds16(Kp + (size_t)rs0 * HDIM + cs0 * 8, &lK[0][wave * 64]);
  gload_lds16(Vp + (size_t)rs0 * SS + cs0 * 8, &lV[0][wave * 64]);

  f32x4 bA0 = *reinterpret_cast<const f32x4*>(Bp + 0 * 16 + l4 * 4);
  f32x4 bA1 = *reinterpret_cast<const f32x4*>(Bp + 1 * 16 + l4 * 4);
  f32x4 bA2 = *reinterpret_cast<const f32x4*>(Bp + 2 * 16 + l4 * 4);
  f32x4 bA3 = *reinterpret_cast<const f32x4*>(Bp + 3 * 16 + l4 * 4);
  f32x4 bB0 = bA0, bB1 = bA1, bB2 = bA2, bB3 = bA3;

  bf16x8 qf[2];
#pragma unroll
  for (int ks = 0; ks < 2; ++ks)
    qf[ks] = *reinterpret_cast<const bf16x8*>(Qp + (size_t)l15 * HDIM +
                                              ks * 32 + l4 * 8);
  const f32x4 z = {0.f, 0.f, 0.f, 0.f};
  f32x4 o[4];
#pragma unroll
  for (int dd = 0; dd < 4; ++dd) o[dd] = z;
  float mrow = -1e30f, lrow = 0.f;

  __syncthreads();  // tile 0 staged (barrier drains vmcnt)

#define JJROW(JJ, BC)                                                     \
  {                                                                       \
    const unsigned nib = (unsigned)(mb >> ((JJ)*16 + l4 * 4)) & 15u;      \
    _Pragma("unroll") for (int r = 0; r < 4; ++r) {                       \
      const float a = ((nib >> r) & 1u) ? -1e30f : (BC)[r];               \
      v[JJ][r] = fmaf(sc[JJ][r], 0.125f, a);                              \
      bm = fmaxf(bm, v[JJ][r]);                                           \
    }                                                                     \
  }

#define STEP(T, BC0, BC1, BC2, BC3, BN0, BN1, BN2, BN3)                        \
  {                                                                            \
    const int cur = (T)&1;                                                     \
    const int nxt = cur ^ 1;                                                   \
    const int kbn = ((T) + 1) * 64;                                            \
    const bool pf = (T) < 31;                                                  \
    if (pf) {                                                                  \
      BN0 = *reinterpret_cast<const f32x4*>(Bp + kbn + 0 * 16 + l4 * 4);       \
      BN1 = *reinterpret_cast<const f32x4*>(Bp + kbn + 1 * 16 + l4 * 4);       \
      BN2 = *reinterpret_cast<const f32x4*>(Bp + kbn + 2 * 16 + l4 * 4);       \
      BN3 = *reinterpret_cast<const f32x4*>(Bp + kbn + 3 * 16 + l4 * 4);       \
    }                                                                          \
    f32x4 sc[4];                                                               \
    __builtin_amdgcn_s_setprio(1);                                             \
    _Pragma("unroll") for (int jj = 0; jj < 4; ++jj) {                         \
      const int R = jj * 16 + l15;                                             \
      bf16x8 kf0 = lK[cur][R * 8 + ((0 + l4) ^ (R & 7))];                      \
      bf16x8 kf1 = lK[cur][R * 8 + ((4 + l4) ^ (R & 7))];                      \
      f32x4 s = mfma16(kf0, qf[0], z);                                         \
      s = mfma16(kf1, qf[1], s);                                               \
      sc[jj] = s;                                                              \
    }                                                                          \
    __builtin_amdgcn_s_setprio(0);                                             \
    if (pf) { /* K-stage: after all lK[cur] reads */                           \
      gload_lds16(Kp + (size_t)(kbn + rs0) * HDIM + cs0 * 8,                   \
                  &lK[nxt][wave * 64]);                                        \
    }                                                                          \
    const unsigned long long mb = mbits[(b << 5) + (T)];                       \
    float v[4][4];                                                             \
    float bm = -1e30f;                                                         \
    JJROW(0, BC0)                                                              \
    JJROW(1, BC1)                                                              \
    JJROW(2, BC2)                                                              \
    JJROW(3, BC3)                                                              \
    bm = fmaxf(bm, __shfl_xor(bm, 16));                                        \
    bm = fmaxf(bm, __shfl_xor(bm, 32));                                        \
    const bool resc = __any(bm > mrow + 8.0f);                                 \
    float alpha = 1.0f;                                                        \
    if (resc) {                                                                \
      const float mn = fmaxf(mrow, bm);                                        \
      alpha = __expf(mrow - mn);                                               \
      mrow = mn;                                                               \
    }                                                                          \
    float ps = 0.f;                                                            \
    float p[4][4];                                                             \
    _Pragma("unroll") for (int jj = 0; jj < 4; ++jj)                           \
        _Pragma("unroll") for (int r = 0; r < 4; ++r) {                        \
      p[jj][r] = __expf(v[jj][r] - mrow);                                      \
      ps += p[jj][r];                                                          \
    }                                                                          \
    ps += __shfl_xor(ps, 16);                                                  \
    ps += __shfl_xor(ps, 32);                                                  \
    lrow = lrow * alpha + ps;                                                  \
    _Pragma("unroll") for (int jj = 0; jj < 4; ++jj) {                         \
      union {                                                                  \
        bf16 h4[4];                                                            \
        unsigned long long w;                                                  \
      } u;                                                                     \
      u.h4[0] = __float2bfloat16(p[jj][0]);                                    \
      u.h4[1] = __float2bfloat16(p[jj][1]);                                    \
      u.h4[2] = __float2bfloat16(p[jj][2]);                                    \
      u.h4[3] = __float2bfloat16(p[jj][3]);                                    \
      const int byte = (l15 * 128 + jj * 32 + l4 * 8) ^ ((l15 & 7) << 4);      \
      *reinterpret_cast<unsigned long long*>(                                  \
          reinterpret_cast<char*>(plw) + byte) = u.w;                          \
    }                                                                          \
    bf16x8 vfr[4][2];                                                          \
    _Pragma("unroll") for (int dd = 0; dd < 4; ++dd) {                         \
      const int D = dd * 16 + l15;                                             \
      vfr[dd][0] = lV[cur][D * 8 + ((0 + l4) ^ (D & 7))];                      \
      vfr[dd][1] = lV[cur][D * 8 + ((4 + l4) ^ (D & 7))];                      \
    }                                                                          \
    if (pf) { /* V-stage: after all lV[cur] reads */                           \
      gload_lds16(Vp + (size_t)rs0 * SS + kbn + cs0 * 8,                       \
                  &lV[nxt][wave * 64]);                                        \
    }                                                                          \
    asm volatile("s_waitcnt lgkmcnt(0)" ::: "memory");                         \
    bf16x8 pfr[2];                                                             \
    _Pragma("unroll") for (int ks = 0; ks < 2; ++ks) {                         \
      const int byte = (l15 * 128 + ks * 64 + l4 * 16) ^ ((l15 & 7) << 4);     \
      pfr[ks] = *reinterpret_cast<const bf16x8*>(                              \
          reinterpret_cast<const char*>(plw) + byte);                          \
    }                                                                          \
    if (resc) {                                                                \
      float ar0 = __shfl(alpha, l4 * 4 + 0);                                   \
      float ar1 = __shfl(alpha, l4 * 4 + 1);                                   \
      float ar2 = __shfl(alpha, l4 * 4 + 2);                                   \
      float ar3 = __shfl(alpha, l4 * 4 + 3);                                   \
      _Pragma("unroll") for (int dd = 0; dd < 4; ++dd) {                       \
        o[dd][0] *= ar0;                                                       \
        o[dd][1] *= ar1;                                                       \
        o[dd][2] *= ar2;                                                       \
        o[dd][3] *= ar3;                                                       \
      }                                                                        \
    }                                                                          \
    __builtin_amdgcn_s_setprio(1);                                             \
    _Pragma("unroll") for (int dd = 0; dd < 4; ++dd) {                         \
      o[dd] = mfma16(pfr[0], vfr[dd][0], o[dd]);                               \
      o[dd] = mfma16(pfr[1], vfr[dd][1], o[dd]);                               \
    }                                                                          \
    __builtin_amdgcn_s_setprio(0);                                             \
    __syncthreads();                                                           \
  }

  for (int t2 = 0; t2 < 16; ++t2) {
    const int te = t2 * 2;
    STEP(te, bA0, bA1, bA2, bA3, bB0, bB1, bB2, bB3)
    STEP(te + 1, bB0, bB1, bB2, bB3, bA0, bA1, bA2, bA3)
  }
#undef STEP
#undef JJROW

  const float rl = 1.0f / lrow;
  float rlr[4];
#pragma unroll
  for (int r = 0; r < 4; ++r) rlr[r] = __shfl(rl, l4 * 4 + r);
#pragma unroll
  for (int dd = 0; dd < 4; ++dd) {
#pragma unroll
    for (int r = 0; r < 4; ++r) {
      const float val = o[dd][r] * rlr[r];
      const int s = q0w + l4 * 4 + r;
      ctx[((size_t)b * SS + s) * DDIM + h * HDIM + dd * 16 + l15] =
          __float2bfloat16(val);
    }
  }
}

extern "C" void kernel_launch(void* const* d_in, const int* in_sizes, int n_in,
                              void* d_out, int out_size, void* d_ws,
                              size_t ws_size, hipStream_t stream) {
  const float* x = (const float*)d_in[0];
  const float* abias = (const float*)d_in[1];
  const int* kpm = (const int*)d_in[2];
  const float* Wq = (const float*)d_in[3];
  const float* bq = (const float*)d_in[4];
  const float* Wk = (const float*)d_in[5];
  const float* bk = (const float*)d_in[6];
  const float* Wv = (const float*)d_in[7];
  const float* bv = (const float*)d_in[8];
  const float* Wo = (const float*)d_in[9];
  const float* bo = (const float*)d_in[10];
  float* out = (float*)d_out;

  char* ws = (char*)d_ws;
  bf16* xb = (bf16*)ws;                        // (B,S,D) bf16      8 MB
  bf16* Wt = (bf16*)(ws + 8388608);            // 3072x1024 bf16    6 MB
  bf16* Wot = (bf16*)(ws + 14680064);          // 1024x1024 bf16    2 MB
  bf16* Qb = (bf16*)(ws + 16777216);           // (B,H,S,HD)        8 MB
  bf16* Kb = (bf16*)(ws + 25165824);           // (B,H,S,HD)        8 MB
  bf16* Vtb = (bf16*)(ws + 33554432);          // (B,H,HD,S)        8 MB
  bf16* ctx = (bf16*)(ws + 41943040);          // (B,S,D) bf16      8 MB
  unsigned long long* mbits =
      (unsigned long long*)(ws + 50331648);    // 2*32 u64

  dim3 t256(256);
  cvt_k<<<dim3(2048), t256, 0, stream>>>(x, xb);
  transpose_cvt4_k<<<dim3(16, 16, 4), t256, 0, stream>>>(
      Wq, Wk, Wv, Wo, Wt, Wt + 1024 * 1024, Wt + 2 * 1024 * 1024, Wot);
  mask_pack_k<<<dim3(64), dim3(64), 0, stream>>>(kpm, mbits);

  gemm_bt<0><<<dim3(32, 24), t256, 0, stream>>>(xb, Wt, bq, bk, bv, Qb, Kb,
                                                Vtb, nullptr);
  attn_k<<<dim3(512), dim3(512), 0, stream>>>(Qb, Kb, Vtb, abias, mbits, ctx);
  gemm_bt<1><<<dim3(32, 8), t256, 0, stream>>>(ctx, Wot, bo, nullptr, nullptr,
                                               nullptr, nullptr, nullptr, out);
}